// Round 13
// baseline (148.679 us; speedup 1.0000x reference)
//
#include <hip/hip_runtime.h>
#include <hip/hip_bf16.h>
#include <cstdint>

#define B 32
#define L 512
#define T 2048
#define M 80
#define KDIM 160

#define NEG_INF (-1e30f)
#define LOG_2PI 1.8378770664093453f

typedef uint32_t u32;
typedef unsigned short u16;
typedef u16 u16x8 __attribute__((ext_vector_type(8)));
typedef short bf16x8 __attribute__((ext_vector_type(8)));
typedef float f32x4 __attribute__((ext_vector_type(4)));

// robust to harness passing lengths as int32 or int64 (values are small positive;
// if int64, word[1] == high word of elem0 == 0; if int32, word[1] in [64,2048] != 0)
__device__ __forceinline__ int get_len(const int* __restrict__ p, int b) {
  return (p[1] == 0) ? p[2 * b] : p[b];
}

__device__ __forceinline__ u16 f2bf(float f) {
  __hip_bfloat16 h = __float2bfloat16(f);
  return *(u16*)&h;
}

// ---------------- prep: Wfrag[b][kc][l][8] (bf16 B-fragments), bias[b][l] --------
__global__ __launch_bounds__(256) void prep_kernel(const float* __restrict__ mu_sigma,
                                                   u16* __restrict__ Wfrag,
                                                   float* __restrict__ biasv) {
  int gid = blockIdx.x * 256 + threadIdx.x;  // b*L + l
  if (gid >= B * L) return;
  int b = gid >> 9;
  int l = gid & (L - 1);
  const float* row = mu_sigma + (size_t)gid * (2 * M);
  float acc_a = 0.f, acc_ls = 0.f;
#pragma unroll 2
  for (int g = 0; g < 10; ++g) {
    u16x8 wsq, wli;
#pragma unroll
    for (int j = 0; j < 8; ++j) {
      float mu = row[g * 8 + j];
      float ls = row[M + g * 8 + j];
      float iv = expf(-2.f * ls);
      acc_a += mu * mu * iv;
      acc_ls += ls;
      wsq[j] = f2bf(-0.5f * iv);
      wli[j] = f2bf(mu * iv);
    }
    *(u16x8*)(Wfrag + ((size_t)(b * 20 + g) * L + l) * 8) = wsq;
    *(u16x8*)(Wfrag + ((size_t)(b * 20 + 10 + g) * L + l) * 8) = wli;
  }
  biasv[gid] = -0.5f * acc_a - (0.5f * (float)M * LOG_2PI + 0.5f * acc_ls);
}

// ---------------- xprep: Xfrag[b][kc][t][8] (bf16 A-fragments) ----------------
__global__ __launch_bounds__(256) void xprep_kernel(const float* __restrict__ melspec,
                                                    u16* __restrict__ Xfrag) {
  int gid = blockIdx.x * 256 + threadIdx.x;  // (b*10 + mg)*T + t
  int t = gid & (T - 1);
  int rest = gid >> 11;
  int mg = rest % 10;
  int b = rest / 10;
  u16x8 sq, li;
#pragma unroll
  for (int j = 0; j < 8; ++j) {
    float xv = melspec[((size_t)b * M + mg * 8 + j) * T + t];
    sq[j] = f2bf(xv * xv);
    li[j] = f2bf(xv);
  }
  *(u16x8*)(Xfrag + ((size_t)(b * 20 + mg) * T + t) * 8) = sq;
  *(u16x8*)(Xfrag + ((size_t)(b * 20 + 10 + mg) * T + t) * 8) = li;
}

// ---------------- gemm (MFMA): logpT[b][t][l] bf16 = bias + sum_k X*W ----------
__global__ __launch_bounds__(256) void gemm_logp(const u16* __restrict__ Xfrag,
                                                 const u16* __restrict__ Wfrag,
                                                 const float* __restrict__ biasv,
                                                 const int* __restrict__ mel_len,
                                                 const int* __restrict__ text_len,
                                                 u16* __restrict__ logpT,
                                                 int t_begin, int tc) {
  int b = blockIdx.z;
  int t0 = t_begin + blockIdx.x * 64;
  int l0 = blockIdx.y * 128;
  if (t0 >= get_len(mel_len, b)) return;
  if (l0 >= get_len(text_len, b)) return;

  int tid = threadIdx.x;
  int wave = tid >> 6, lane = tid & 63;
  int wt = wave >> 1, wl = wave & 1;
  int mbase = t0 + wt * 32;
  int nbase = l0 + wl * 64;
  int l16 = lane & 15, khalf = lane >> 4;

  const bf16x8* Xp = (const bf16x8*)Xfrag;
  const bf16x8* Wp = (const bf16x8*)Wfrag;

  f32x4 acc[2][4];
#pragma unroll
  for (int i = 0; i < 2; ++i)
#pragma unroll
    for (int j = 0; j < 4; ++j) acc[i][j] = (f32x4){0.f, 0.f, 0.f, 0.f};

#pragma unroll
  for (int ks = 0; ks < 5; ++ks) {
    int kc = ks * 4 + khalf;
    size_t xb = (size_t)(b * 20 + kc) * T;
    size_t wb = (size_t)(b * 20 + kc) * L;
    bf16x8 a0 = Xp[xb + mbase + l16];
    bf16x8 a1 = Xp[xb + mbase + 16 + l16];
    bf16x8 b0 = Wp[wb + nbase + l16];
    bf16x8 b1 = Wp[wb + nbase + 16 + l16];
    bf16x8 b2 = Wp[wb + nbase + 32 + l16];
    bf16x8 b3 = Wp[wb + nbase + 48 + l16];
    acc[0][0] = __builtin_amdgcn_mfma_f32_16x16x32_bf16(a0, b0, acc[0][0], 0, 0, 0);
    acc[0][1] = __builtin_amdgcn_mfma_f32_16x16x32_bf16(a0, b1, acc[0][1], 0, 0, 0);
    acc[0][2] = __builtin_amdgcn_mfma_f32_16x16x32_bf16(a0, b2, acc[0][2], 0, 0, 0);
    acc[0][3] = __builtin_amdgcn_mfma_f32_16x16x32_bf16(a0, b3, acc[0][3], 0, 0, 0);
    acc[1][0] = __builtin_amdgcn_mfma_f32_16x16x32_bf16(a1, b0, acc[1][0], 0, 0, 0);
    acc[1][1] = __builtin_amdgcn_mfma_f32_16x16x32_bf16(a1, b1, acc[1][1], 0, 0, 0);
    acc[1][2] = __builtin_amdgcn_mfma_f32_16x16x32_bf16(a1, b2, acc[1][2], 0, 0, 0);
    acc[1][3] = __builtin_amdgcn_mfma_f32_16x16x32_bf16(a1, b3, acc[1][3], 0, 0, 0);
  }

  // epilogue: C/D map col = lane&15, row = khalf*4 + r  [verified m89/m91]
  int rbase = khalf * 4;
#pragma unroll
  for (int j = 0; j < 4; ++j) {
    int colL = nbase + j * 16 + l16;
    float bias = biasv[b * L + colL];
#pragma unroll
    for (int i = 0; i < 2; ++i) {
#pragma unroll
      for (int r = 0; r < 4; ++r) {
        int t = mbase + i * 16 + rbase + r;
        logpT[((size_t)b * tc + (t - t_begin)) * L + colL] = f2bf(acc[i][j][r] + bias);
      }
    }
  }
}

// ---------------- scan: producer/consumer waves, halo-redundant max-plus --------
// 8 waves. Wave 7 = PRODUCER: stages 32-row phases of logpT into a 2-phase LDS
// ring via global_load_lds (1 row = 1KB = 64 lanes x 16B), counted vmcnt(32)
// before each barrier guarantees the next phase landed; one full phase (~1400cy)
// of lookahead covers HBM latency. Waves 0-6 = CONSUMERS: wave w covers cols
// [64w, 64w+128) (2/lane); per 8-row block: 8 hoisted ds_read_b32 (4B/lane,
// 2-way bank alias = free) + one lgkmcnt(0), then 8 unconstrained VALU steps.
// Registers stay tiny (~25 VGPR) -> nothing for the allocator to shunt to AGPRs
// (the silent serializer of R7/R9/R11/R12). Halo exchange merges into the phase
// barrier every 2 phases (64 steps, proven cadence). All barriers convergent.
#define SROWS 32

#define VMW(n)                                             \
  do {                                                     \
    asm volatile("s_waitcnt vmcnt(" #n ")" ::: "memory");  \
    __builtin_amdgcn_sched_barrier(0);                     \
  } while (0)
#define DS_READ_B32(dst, addr, imm) \
  asm volatile("ds_read_b32 %0, %1 offset:" #imm : "=v"(dst) : "v"(addr))
#define LGKM0()                                            \
  do {                                                     \
    asm volatile("s_waitcnt lgkmcnt(0)" ::: "memory");     \
    __builtin_amdgcn_sched_barrier(0);                     \
  } while (0)

// 8-row block: hoist all reads, wait once, compute freely.
#define CBLK(basea_)                         \
  do {                                       \
    u32 q0, q1, q2, q3, q4, q5, q6, q7;      \
    DS_READ_B32(q0, basea_, 0);              \
    DS_READ_B32(q1, basea_, 1024);           \
    DS_READ_B32(q2, basea_, 2048);           \
    DS_READ_B32(q3, basea_, 3072);           \
    DS_READ_B32(q4, basea_, 4096);           \
    DS_READ_B32(q5, basea_, 5120);           \
    DS_READ_B32(q6, basea_, 6144);           \
    DS_READ_B32(q7, basea_, 7168);           \
    LGKM0();                                 \
    stepu(q0); stepu(q1); stepu(q2); stepu(q3); \
    stepu(q4); stepu(q5); stepu(q6); stepu(q7); \
  } while (0)

__device__ __forceinline__ float dpp_shr1_neginf(float x) {
  int r = __builtin_amdgcn_update_dpp(__float_as_int(NEG_INF), __float_as_int(x),
                                      0x138, 0xf, 0xf, false);  // wave_shr:1
  return __int_as_float(r);
}

__global__ __launch_bounds__(512, 2) void scan_kernel(const u16* __restrict__ logpT,
                                                      const int* __restrict__ mel_len,
                                                      const int* __restrict__ text_len,
                                                      float* __restrict__ carry_ws,
                                                      float* __restrict__ la_ws,
                                                      int t_begin, int tc) {
  __shared__ u16 ring[2][SROWS][L];   // 64 KB
  __shared__ float smem[2][L];        // 4 KB halo exchange
  int tid = threadIdx.x;
  int wave = tid >> 6;
  int lane = tid & 63;
  int b = blockIdx.x;
  int ml = get_len(mel_len, b);
  int tl = get_len(text_len, b);
  const u16* base0 = logpT + (size_t)b * tc * L;
  float* cws = carry_ws + b * L;
  bool prod = (wave == 7);
  int col0 = 64 * wave + 2 * lane;                  // consumers only
  bool owner = !prod && ((wave == 0) || (lane >= 32));

  float c0 = NEG_INF, c1 = NEG_INF;
  int tstart;
  if (t_begin == 0) {
    if (tid == 0) c0 = __uint_as_float((u32)base0[0] << 16);  // logp[b,0,0]
    tstart = 1;
  } else {
    if (!prod) {
      float2 v = *(const float2*)(cws + col0);
      c0 = v.x; c1 = v.y;
    }
    tstart = t_begin;
  }

  int tstop = min(t_begin + tc, ml);
  int nrows = tstop - tstart;

  auto stepu = [&](u32 v) {
    float p = dpp_shr1_neginf(c1);  // lane-1's old c1; lane0 <- NEG_INF (halo edge)
    float f0 = __uint_as_float(v << 16);
    float f1 = __uint_as_float(v & 0xFFFF0000u);
    c1 = fmaxf(c1, c0) + f1;
    c0 = fmaxf(c0, p) + f0;
  };

  if (nrows > 0) {
    int np = (nrows + SROWS - 1) / SROWS;
    int tlast = tstop - 1;

    auto stage = [&](int ph) -> bool {  // producer wave only
      if (ph >= np) return false;
      int pstart = tstart + ph * SROWS;
      u16* dst0 = &ring[ph & 1][0][0];
#pragma unroll
      for (int r = 0; r < SROWS; ++r) {
        int t = pstart + r;
        t = (t > tlast) ? tlast : t;  // clamp (dups unread by consumers)
        const u16* s = base0 + (size_t)(t - t_begin) * L + lane * 8;
        __builtin_amdgcn_global_load_lds(
            (const __attribute__((address_space(1))) void*)s,
            (__attribute__((address_space(3))) void*)(dst0 + (size_t)r * L + lane * 8),
            16, 0, 0);
      }
      return true;
    };

    if (prod) {
      bool s1;
      stage(0);
      s1 = stage(1);
      if (s1) VMW(32); else VMW(0);  // phase 0 landed
    }
    __syncthreads();

    for (int k = 0; k < np; ++k) {
      if (prod) {
        if (stage(k + 2)) VMW(32);   // waits phase k+1 complete
        else              VMW(0);
      } else {
        int pstart = tstart + k * SROWS;
        int rem = tstop - pstart;
        if (rem > SROWS) rem = SROWS;
        u32 ringA = (u32)(uintptr_t)(__attribute__((address_space(3)))
                                     u16*)(&ring[k & 1][0][0]) +
                    128u * (u32)wave + 4u * (u32)lane;
        if (rem == SROWS) {
          CBLK(ringA);
          CBLK(ringA + 8192);
          CBLK(ringA + 16384);
          CBLK(ringA + 24576);
        } else {
          const char* rp = (const char*)(&ring[k & 1][0][0]) + 128 * wave + 4 * lane;
          for (int r = 0; r < rem; ++r) {
            u32 v = *(const u32*)(rp + (size_t)r * (L * 2));
            stepu(v);
          }
        }
        if ((k & 1) && owner) {  // halo publish every 2 phases (64 steps)
          smem[(k >> 1) & 1][col0] = c0;
          smem[(k >> 1) & 1][col0 + 1] = c1;
        }
      }
      __syncthreads();
      if ((k & 1) && !prod && wave > 0 && lane < 32) {  // halo refresh
        c0 = smem[(k >> 1) & 1][col0];
        c1 = smem[(k >> 1) & 1][col0 + 1];
      }
    }
  }

  // persist carry (owned cols only)
  if (owner) *(float2*)(cws + col0) = make_float2(c0, c1);

  if (t_begin + tc >= T) {  // last chunk: la[b] = alpha[ml-1][tl-1]
    int li = tl - 1;
    int w_own = (li < 128) ? 0 : ((li >> 6) - 1);
    if (!prod && wave == w_own) {
      int local = li - 64 * w_own;
      float v = (local & 1) ? c1 : c0;
      float lav = __shfl(v, local >> 1);
      if (lane == 0) la_ws[b] = lav;
    }
  }
}

__global__ __launch_bounds__(64) void reduce_kernel(const float* __restrict__ la_ws,
                                                    float* __restrict__ out) {
  int lane = threadIdx.x;
  float v = (lane < B) ? la_ws[lane] : 0.f;
#pragma unroll
  for (int s = 32; s > 0; s >>= 1) v += __shfl_down(v, s);
  if (lane == 0) out[0] = -v * (1.0f / (float)B);
}

extern "C" void kernel_launch(void* const* d_in, const int* in_sizes, int n_in,
                              void* d_out, int out_size, void* d_ws, size_t ws_size,
                              hipStream_t stream) {
  const float* mu_sigma = (const float*)d_in[0];
  const float* melspec  = (const float*)d_in[1];
  const int*   text_len = (const int*)d_in[2];
  const int*   mel_len  = (const int*)d_in[3];
  float* out = (float*)d_out;

  char* ws = (char*)d_ws;
  size_t off = 0;
  u16* Wfrag = (u16*)(ws + off);         off += (size_t)B * KDIM * L * 2;      // 5.2 MB
  float* biasv = (float*)(ws + off);     off += (size_t)B * L * 4;
  float* carry_ws = (float*)(ws + off);  off += (size_t)B * L * 4;
  float* la_ws = (float*)(ws + off);     off += 256;
  u16* Xfrag = (u16*)(ws + off);         off += (size_t)B * KDIM * T * 2;      // 21 MB
  u16* logpT = (u16*)(ws + off);
  size_t avail = (ws_size > off) ? (ws_size - off) : 0;
  size_t per_t = (size_t)B * L * 2;  // bytes per t-slice across all b (bf16)
  long long tcl = (long long)(avail / per_t);
  int Tc = (tcl > T) ? T : (int)tcl;
  Tc &= ~63;
  if (Tc < 64) return;  // insufficient workspace (not expected)

  prep_kernel<<<dim3((B * L + 255) / 256), 256, 0, stream>>>(mu_sigma, Wfrag, biasv);
  xprep_kernel<<<dim3((B * 10 * T) / 256), 256, 0, stream>>>(melspec, Xfrag);

  for (int t_begin = 0; t_begin < T; t_begin += Tc) {
    int tc = (T - t_begin < Tc) ? (T - t_begin) : Tc;
    dim3 grid(tc / 64, L / 128, B);
    gemm_logp<<<grid, 256, 0, stream>>>(Xfrag, Wfrag, biasv, mel_len, text_len,
                                        logpT, t_begin, tc);
    scan_kernel<<<dim3(B), 512, 0, stream>>>(logpT, mel_len, text_len, carry_ws,
                                             la_ws, t_begin, tc);
  }
  reduce_kernel<<<1, 64, 0, stream>>>(la_ws, out);
}

// Round 14
// 145.427 us; speedup vs baseline: 1.0224x; 1.0224x over previous
//
#include <hip/hip_runtime.h>
#include <hip/hip_bf16.h>
#include <cstdint>

#define B 32
#define L 512
#define T 2048
#define M 80
#define KDIM 160

#define NEG_INF (-1e30f)
#define LOG_2PI 1.8378770664093453f

typedef uint32_t u32;
typedef unsigned short u16;
typedef u16 u16x8 __attribute__((ext_vector_type(8)));
typedef short bf16x8 __attribute__((ext_vector_type(8)));
typedef float f32x4 __attribute__((ext_vector_type(4)));

// robust to harness passing lengths as int32 or int64 (values are small positive;
// if int64, word[1] == high word of elem0 == 0; if int32, word[1] in [64,2048] != 0)
__device__ __forceinline__ int get_len(const int* __restrict__ p, int b) {
  return (p[1] == 0) ? p[2 * b] : p[b];
}

__device__ __forceinline__ u16 f2bf(float f) {
  __hip_bfloat16 h = __float2bfloat16(f);
  return *(u16*)&h;
}

// ---------------- prep: Wfrag[b][kc][l][8] (bf16 B-fragments), bias[b][l] --------
__global__ __launch_bounds__(256) void prep_kernel(const float* __restrict__ mu_sigma,
                                                   u16* __restrict__ Wfrag,
                                                   float* __restrict__ biasv) {
  int gid = blockIdx.x * 256 + threadIdx.x;  // b*L + l
  if (gid >= B * L) return;
  int b = gid >> 9;
  int l = gid & (L - 1);
  const float* row = mu_sigma + (size_t)gid * (2 * M);
  float acc_a = 0.f, acc_ls = 0.f;
#pragma unroll 2
  for (int g = 0; g < 10; ++g) {
    u16x8 wsq, wli;
#pragma unroll
    for (int j = 0; j < 8; ++j) {
      float mu = row[g * 8 + j];
      float ls = row[M + g * 8 + j];
      float iv = expf(-2.f * ls);
      acc_a += mu * mu * iv;
      acc_ls += ls;
      wsq[j] = f2bf(-0.5f * iv);
      wli[j] = f2bf(mu * iv);
    }
    *(u16x8*)(Wfrag + ((size_t)(b * 20 + g) * L + l) * 8) = wsq;
    *(u16x8*)(Wfrag + ((size_t)(b * 20 + 10 + g) * L + l) * 8) = wli;
  }
  biasv[gid] = -0.5f * acc_a - (0.5f * (float)M * LOG_2PI + 0.5f * acc_ls);
}

// ---------------- xprep: Xfrag[b][kc][t][8] (bf16 A-fragments) ----------------
__global__ __launch_bounds__(256) void xprep_kernel(const float* __restrict__ melspec,
                                                    u16* __restrict__ Xfrag) {
  int gid = blockIdx.x * 256 + threadIdx.x;  // (b*10 + mg)*T + t
  int t = gid & (T - 1);
  int rest = gid >> 11;
  int mg = rest % 10;
  int b = rest / 10;
  u16x8 sq, li;
#pragma unroll
  for (int j = 0; j < 8; ++j) {
    float xv = melspec[((size_t)b * M + mg * 8 + j) * T + t];
    sq[j] = f2bf(xv * xv);
    li[j] = f2bf(xv);
  }
  *(u16x8*)(Xfrag + ((size_t)(b * 20 + mg) * T + t) * 8) = sq;
  *(u16x8*)(Xfrag + ((size_t)(b * 20 + 10 + mg) * T + t) * 8) = li;
}

// ---------------- gemm (MFMA): logpT[b][t][l] bf16 = bias + sum_k X*W ----------
__global__ __launch_bounds__(256) void gemm_logp(const u16* __restrict__ Xfrag,
                                                 const u16* __restrict__ Wfrag,
                                                 const float* __restrict__ biasv,
                                                 const int* __restrict__ mel_len,
                                                 const int* __restrict__ text_len,
                                                 u16* __restrict__ logpT,
                                                 int t_begin, int tc) {
  int b = blockIdx.z;
  int t0 = t_begin + blockIdx.x * 64;
  int l0 = blockIdx.y * 128;
  if (t0 >= get_len(mel_len, b)) return;
  if (l0 >= get_len(text_len, b)) return;

  int tid = threadIdx.x;
  int wave = tid >> 6, lane = tid & 63;
  int wt = wave >> 1, wl = wave & 1;
  int mbase = t0 + wt * 32;
  int nbase = l0 + wl * 64;
  int l16 = lane & 15, khalf = lane >> 4;

  const bf16x8* Xp = (const bf16x8*)Xfrag;
  const bf16x8* Wp = (const bf16x8*)Wfrag;

  f32x4 acc[2][4];
#pragma unroll
  for (int i = 0; i < 2; ++i)
#pragma unroll
    for (int j = 0; j < 4; ++j) acc[i][j] = (f32x4){0.f, 0.f, 0.f, 0.f};

#pragma unroll
  for (int ks = 0; ks < 5; ++ks) {
    int kc = ks * 4 + khalf;
    size_t xb = (size_t)(b * 20 + kc) * T;
    size_t wb = (size_t)(b * 20 + kc) * L;
    bf16x8 a0 = Xp[xb + mbase + l16];
    bf16x8 a1 = Xp[xb + mbase + 16 + l16];
    bf16x8 b0 = Wp[wb + nbase + l16];
    bf16x8 b1 = Wp[wb + nbase + 16 + l16];
    bf16x8 b2 = Wp[wb + nbase + 32 + l16];
    bf16x8 b3 = Wp[wb + nbase + 48 + l16];
    acc[0][0] = __builtin_amdgcn_mfma_f32_16x16x32_bf16(a0, b0, acc[0][0], 0, 0, 0);
    acc[0][1] = __builtin_amdgcn_mfma_f32_16x16x32_bf16(a0, b1, acc[0][1], 0, 0, 0);
    acc[0][2] = __builtin_amdgcn_mfma_f32_16x16x32_bf16(a0, b2, acc[0][2], 0, 0, 0);
    acc[0][3] = __builtin_amdgcn_mfma_f32_16x16x32_bf16(a0, b3, acc[0][3], 0, 0, 0);
    acc[1][0] = __builtin_amdgcn_mfma_f32_16x16x32_bf16(a1, b0, acc[1][0], 0, 0, 0);
    acc[1][1] = __builtin_amdgcn_mfma_f32_16x16x32_bf16(a1, b1, acc[1][1], 0, 0, 0);
    acc[1][2] = __builtin_amdgcn_mfma_f32_16x16x32_bf16(a1, b2, acc[1][2], 0, 0, 0);
    acc[1][3] = __builtin_amdgcn_mfma_f32_16x16x32_bf16(a1, b3, acc[1][3], 0, 0, 0);
  }

  // epilogue: C/D map col = lane&15, row = khalf*4 + r  [verified m89/m91]
  int rbase = khalf * 4;
#pragma unroll
  for (int j = 0; j < 4; ++j) {
    int colL = nbase + j * 16 + l16;
    float bias = biasv[b * L + colL];
#pragma unroll
    for (int i = 0; i < 2; ++i) {
#pragma unroll
      for (int r = 0; r < 4; ++r) {
        int t = mbase + i * 16 + rbase + r;
        logpT[((size_t)b * tc + (t - t_begin)) * L + colL] = f2bf(acc[i][j][r] + bias);
      }
    }
  }
}

// ---------------- scan: 7 symmetric waves, raw-barrier phase pipeline ----------
// KEY FIX vs R10-R13: __syncthreads() emits s_waitcnt vmcnt(0) before s_barrier,
// draining ALL in-flight global_load_lds every phase -> pipeline never survived a
// barrier. Here: raw __builtin_amdgcn_s_barrier() + hand-placed counted waits.
// Wave w computes cols [64w,64w+128) (2/lane), owns top 64 (wave0 all 128); halo
// degrades 1 col/step, refreshed every 56-step phase (<64 ok). Each wave stages
// its own 8 rows/phase into a 2-slot LDS ring; vmcnt(8) waits only its own
// previous-phase loads; barriers do NOT drain DMA.
#define SROWS 56

#define VMW(n)                                             \
  do {                                                     \
    asm volatile("s_waitcnt vmcnt(" #n ")" ::: "memory");  \
    __builtin_amdgcn_sched_barrier(0);                     \
  } while (0)
#define DS_READ_B32(dst, addr, imm) \
  asm volatile("ds_read_b32 %0, %1 offset:" #imm : "=v"(dst) : "v"(addr))
#define LGKM0()                                            \
  do {                                                     \
    asm volatile("s_waitcnt lgkmcnt(0)" ::: "memory");     \
    __builtin_amdgcn_sched_barrier(0);                     \
  } while (0)
#define BAR()                                              \
  do {                                                     \
    asm volatile("" ::: "memory");                         \
    __builtin_amdgcn_s_barrier();                          \
    asm volatile("" ::: "memory");                         \
  } while (0)

// 8-row block: hoist all reads, wait once, compute freely.
#define CBLK(basea_)                            \
  do {                                          \
    u32 q0, q1, q2, q3, q4, q5, q6, q7;         \
    DS_READ_B32(q0, basea_, 0);                 \
    DS_READ_B32(q1, basea_, 1024);              \
    DS_READ_B32(q2, basea_, 2048);              \
    DS_READ_B32(q3, basea_, 3072);              \
    DS_READ_B32(q4, basea_, 4096);              \
    DS_READ_B32(q5, basea_, 5120);              \
    DS_READ_B32(q6, basea_, 6144);              \
    DS_READ_B32(q7, basea_, 7168);              \
    LGKM0();                                    \
    stepu(q0); stepu(q1); stepu(q2); stepu(q3); \
    stepu(q4); stepu(q5); stepu(q6); stepu(q7); \
  } while (0)

__device__ __forceinline__ float dpp_shr1_neginf(float x) {
  int r = __builtin_amdgcn_update_dpp(__float_as_int(NEG_INF), __float_as_int(x),
                                      0x138, 0xf, 0xf, false);  // wave_shr:1
  return __int_as_float(r);
}

__global__ __launch_bounds__(448, 1) void scan_kernel(const u16* __restrict__ logpT,
                                                      const int* __restrict__ mel_len,
                                                      const int* __restrict__ text_len,
                                                      float* __restrict__ carry_ws,
                                                      float* __restrict__ la_ws,
                                                      int t_begin, int tc) {
  __shared__ u16 ring[2][SROWS][L];   // 112 KB
  __shared__ float smem[2][L];        // 4 KB halo exchange
  int tid = threadIdx.x;
  int wave = tid >> 6;
  int lane = tid & 63;
  int b = blockIdx.x;
  int ml = get_len(mel_len, b);
  int tl = get_len(text_len, b);
  const u16* base0 = logpT + (size_t)b * tc * L;
  float* cws = carry_ws + b * L;
  int col0 = 64 * wave + 2 * lane;
  bool owner = (wave == 0) || (lane >= 32);

  float c0 = NEG_INF, c1 = NEG_INF;
  int tstart;
  if (t_begin == 0) {
    if (tid == 0) c0 = __uint_as_float((u32)base0[0] << 16);  // logp[b,0,0]
    tstart = 1;
  } else {
    float2 v = *(const float2*)(cws + col0);
    c0 = v.x; c1 = v.y;
    tstart = t_begin;
  }

  int tstop = min(t_begin + tc, ml);
  int nrows = tstop - tstart;

  auto stepu = [&](u32 v) {
    float p = dpp_shr1_neginf(c1);  // lane-1's old c1; lane0 <- NEG_INF (halo edge)
    float f0 = __uint_as_float(v << 16);
    float f1 = __uint_as_float(v & 0xFFFF0000u);
    c1 = fmaxf(c1, c0) + f1;
    c0 = fmaxf(c0, p) + f0;
  };

  if (nrows > 0) {
    int np = (nrows + SROWS - 1) / SROWS;
    int tlast = tstop - 1;

    auto stage = [&](int ph) -> bool {  // each wave stages its own 8 rows
      if (ph >= np) return false;
      int pr = tstart + ph * SROWS + 8 * wave;
      u16* d0 = &ring[ph & 1][8 * wave][0];
#pragma unroll
      for (int j = 0; j < 8; ++j) {
        int t = pr + j;
        t = (t > tlast) ? tlast : t;  // clamp; dup rows unread by consumers
        const u16* s = base0 + (size_t)(t - t_begin) * L + lane * 8;
        __builtin_amdgcn_global_load_lds(
            (const __attribute__((address_space(1))) void*)s,
            (__attribute__((address_space(3))) void*)(d0 + (size_t)j * L + lane * 8),
            16, 0, 0);
      }
      return true;
    };

    stage(0);
    for (int k = 0; k < np; ++k) {
      BAR();  // slot (k+1)&1 free: phase k-1 readers are done
      bool nx = stage(k + 1);
      if (nx) VMW(8); else VMW(0);  // own phase-k loads landed
      BAR();  // everyone's phase-k loads landed; halo(k-1) visible
      if (k > 0 && wave > 0 && lane < 32) {  // refresh halo cols
        c0 = smem[(k - 1) & 1][col0];
        c1 = smem[(k - 1) & 1][col0 + 1];
      }
      int pstart = tstart + k * SROWS;
      int rem = tstop - pstart;
      if (rem > SROWS) rem = SROWS;
      u32 ringA = (u32)(uintptr_t)(__attribute__((address_space(3)))
                                   u16*)(&ring[k & 1][0][0]) +
                  128u * (u32)wave + 4u * (u32)lane;
      int nb8 = rem >> 3;
      for (int bk = 0; bk < nb8; ++bk) CBLK(ringA + (u32)bk * 8192u);
      if (rem & 7) {
        const char* rp = (const char*)(&ring[k & 1][0][0]) + 128 * wave + 4 * lane;
        for (int r = nb8 << 3; r < rem; ++r) {
          u32 v = *(const u32*)(rp + (size_t)r * (L * 2));
          stepu(v);
        }
      }
      if (owner) {  // publish fresh halo values for next phase
        smem[k & 1][col0] = c0;
        smem[k & 1][col0 + 1] = c1;
      }
      LGKM0();  // ds_writes landed before next barrier
    }
  }

  // persist carry (owned cols only)
  if (owner) *(float2*)(cws + col0) = make_float2(c0, c1);

  if (t_begin + tc >= T) {  // last chunk: la[b] = alpha[ml-1][tl-1]
    int li = tl - 1;
    int w_own = (li < 128) ? 0 : ((li >> 6) - 1);
    if (wave == w_own) {
      int local = li - 64 * w_own;
      float v = (local & 1) ? c1 : c0;
      float lav = __shfl(v, local >> 1);
      if (lane == 0) la_ws[b] = lav;
    }
  }
}

__global__ __launch_bounds__(64) void reduce_kernel(const float* __restrict__ la_ws,
                                                    float* __restrict__ out) {
  int lane = threadIdx.x;
  float v = (lane < B) ? la_ws[lane] : 0.f;
#pragma unroll
  for (int s = 32; s > 0; s >>= 1) v += __shfl_down(v, s);
  if (lane == 0) out[0] = -v * (1.0f / (float)B);
}

extern "C" void kernel_launch(void* const* d_in, const int* in_sizes, int n_in,
                              void* d_out, int out_size, void* d_ws, size_t ws_size,
                              hipStream_t stream) {
  const float* mu_sigma = (const float*)d_in[0];
  const float* melspec  = (const float*)d_in[1];
  const int*   text_len = (const int*)d_in[2];
  const int*   mel_len  = (const int*)d_in[3];
  float* out = (float*)d_out;

  char* ws = (char*)d_ws;
  size_t off = 0;
  u16* Wfrag = (u16*)(ws + off);         off += (size_t)B * KDIM * L * 2;      // 5.2 MB
  float* biasv = (float*)(ws + off);     off += (size_t)B * L * 4;
  float* carry_ws = (float*)(ws + off);  off += (size_t)B * L * 4;
  float* la_ws = (float*)(ws + off);     off += 256;
  u16* Xfrag = (u16*)(ws + off);         off += (size_t)B * KDIM * T * 2;      // 21 MB
  u16* logpT = (u16*)(ws + off);
  size_t avail = (ws_size > off) ? (ws_size - off) : 0;
  size_t per_t = (size_t)B * L * 2;  // bytes per t-slice across all b (bf16)
  long long tcl = (long long)(avail / per_t);
  int Tc = (tcl > T) ? T : (int)tcl;
  Tc &= ~63;
  if (Tc < 64) return;  // insufficient workspace (not expected)

  prep_kernel<<<dim3((B * L + 255) / 256), 256, 0, stream>>>(mu_sigma, Wfrag, biasv);
  xprep_kernel<<<dim3((B * 10 * T) / 256), 256, 0, stream>>>(melspec, Xfrag);

  for (int t_begin = 0; t_begin < T; t_begin += Tc) {
    int tc = (T - t_begin < Tc) ? (T - t_begin) : Tc;
    dim3 grid(tc / 64, L / 128, B);
    gemm_logp<<<grid, 256, 0, stream>>>(Xfrag, Wfrag, biasv, mel_len, text_len,
                                        logpT, t_begin, tc);
    scan_kernel<<<dim3(B), 448, 0, stream>>>(logpT, mel_len, text_len, carry_ws,
                                             la_ws, t_begin, tc);
  }
  reduce_kernel<<<1, 64, 0, stream>>>(la_ws, out);
}

// Round 15
// 140.132 us; speedup vs baseline: 1.0610x; 1.0378x over previous
//
#include <hip/hip_runtime.h>
#include <hip/hip_bf16.h>
#include <cstdint>

#define B 32
#define L 512
#define T 2048
#define M 80
#define KDIM 160

#define NEG_INF (-1e30f)
#define LOG_2PI 1.8378770664093453f

typedef uint32_t u32;
typedef unsigned short u16;
typedef u16 u16x8 __attribute__((ext_vector_type(8)));
typedef short bf16x8 __attribute__((ext_vector_type(8)));
typedef float f32x4 __attribute__((ext_vector_type(4)));
typedef u32 u32x2 __attribute__((ext_vector_type(2)));

// robust to harness passing lengths as int32 or int64 (values are small positive;
// if int64, word[1] == high word of elem0 == 0; if int32, word[1] in [64,2048] != 0)
__device__ __forceinline__ int get_len(const int* __restrict__ p, int b) {
  return (p[1] == 0) ? p[2 * b] : p[b];
}

__device__ __forceinline__ u16 f2bf(float f) {
  __hip_bfloat16 h = __float2bfloat16(f);
  return *(u16*)&h;
}

// ---------------- prep: Wfrag[b][kc][l][8] (bf16 B-fragments), bias[b][l] --------
__global__ __launch_bounds__(256) void prep_kernel(const float* __restrict__ mu_sigma,
                                                   u16* __restrict__ Wfrag,
                                                   float* __restrict__ biasv) {
  int gid = blockIdx.x * 256 + threadIdx.x;  // b*L + l
  if (gid >= B * L) return;
  int b = gid >> 9;
  int l = gid & (L - 1);
  const float* row = mu_sigma + (size_t)gid * (2 * M);
  float acc_a = 0.f, acc_ls = 0.f;
#pragma unroll 2
  for (int g = 0; g < 10; ++g) {
    u16x8 wsq, wli;
#pragma unroll
    for (int j = 0; j < 8; ++j) {
      float mu = row[g * 8 + j];
      float ls = row[M + g * 8 + j];
      float iv = expf(-2.f * ls);
      acc_a += mu * mu * iv;
      acc_ls += ls;
      wsq[j] = f2bf(-0.5f * iv);
      wli[j] = f2bf(mu * iv);
    }
    *(u16x8*)(Wfrag + ((size_t)(b * 20 + g) * L + l) * 8) = wsq;
    *(u16x8*)(Wfrag + ((size_t)(b * 20 + 10 + g) * L + l) * 8) = wli;
  }
  biasv[gid] = -0.5f * acc_a - (0.5f * (float)M * LOG_2PI + 0.5f * acc_ls);
}

// ---------------- xprep: Xfrag[b][kc][t][8] (bf16 A-fragments) ----------------
__global__ __launch_bounds__(256) void xprep_kernel(const float* __restrict__ melspec,
                                                    u16* __restrict__ Xfrag) {
  int gid = blockIdx.x * 256 + threadIdx.x;  // (b*10 + mg)*T + t
  int t = gid & (T - 1);
  int rest = gid >> 11;
  int mg = rest % 10;
  int b = rest / 10;
  u16x8 sq, li;
#pragma unroll
  for (int j = 0; j < 8; ++j) {
    float xv = melspec[((size_t)b * M + mg * 8 + j) * T + t];
    sq[j] = f2bf(xv * xv);
    li[j] = f2bf(xv);
  }
  *(u16x8*)(Xfrag + ((size_t)(b * 20 + mg) * T + t) * 8) = sq;
  *(u16x8*)(Xfrag + ((size_t)(b * 20 + 10 + mg) * T + t) * 8) = li;
}

// ---------------- gemm (MFMA): logpT[b][t][l] bf16 = bias + sum_k X*W ----------
__global__ __launch_bounds__(256) void gemm_logp(const u16* __restrict__ Xfrag,
                                                 const u16* __restrict__ Wfrag,
                                                 const float* __restrict__ biasv,
                                                 const int* __restrict__ mel_len,
                                                 const int* __restrict__ text_len,
                                                 u16* __restrict__ logpT,
                                                 int t_begin, int tc) {
  int b = blockIdx.z;
  int t0 = t_begin + blockIdx.x * 64;
  int l0 = blockIdx.y * 128;
  if (t0 >= get_len(mel_len, b)) return;
  if (l0 >= get_len(text_len, b)) return;

  int tid = threadIdx.x;
  int wave = tid >> 6, lane = tid & 63;
  int wt = wave >> 1, wl = wave & 1;
  int mbase = t0 + wt * 32;
  int nbase = l0 + wl * 64;
  int l16 = lane & 15, khalf = lane >> 4;

  const bf16x8* Xp = (const bf16x8*)Xfrag;
  const bf16x8* Wp = (const bf16x8*)Wfrag;

  f32x4 acc[2][4];
#pragma unroll
  for (int i = 0; i < 2; ++i)
#pragma unroll
    for (int j = 0; j < 4; ++j) acc[i][j] = (f32x4){0.f, 0.f, 0.f, 0.f};

#pragma unroll
  for (int ks = 0; ks < 5; ++ks) {
    int kc = ks * 4 + khalf;
    size_t xb = (size_t)(b * 20 + kc) * T;
    size_t wb = (size_t)(b * 20 + kc) * L;
    bf16x8 a0 = Xp[xb + mbase + l16];
    bf16x8 a1 = Xp[xb + mbase + 16 + l16];
    bf16x8 b0 = Wp[wb + nbase + l16];
    bf16x8 b1 = Wp[wb + nbase + 16 + l16];
    bf16x8 b2 = Wp[wb + nbase + 32 + l16];
    bf16x8 b3 = Wp[wb + nbase + 48 + l16];
    acc[0][0] = __builtin_amdgcn_mfma_f32_16x16x32_bf16(a0, b0, acc[0][0], 0, 0, 0);
    acc[0][1] = __builtin_amdgcn_mfma_f32_16x16x32_bf16(a0, b1, acc[0][1], 0, 0, 0);
    acc[0][2] = __builtin_amdgcn_mfma_f32_16x16x32_bf16(a0, b2, acc[0][2], 0, 0, 0);
    acc[0][3] = __builtin_amdgcn_mfma_f32_16x16x32_bf16(a0, b3, acc[0][3], 0, 0, 0);
    acc[1][0] = __builtin_amdgcn_mfma_f32_16x16x32_bf16(a1, b0, acc[1][0], 0, 0, 0);
    acc[1][1] = __builtin_amdgcn_mfma_f32_16x16x32_bf16(a1, b1, acc[1][1], 0, 0, 0);
    acc[1][2] = __builtin_amdgcn_mfma_f32_16x16x32_bf16(a1, b2, acc[1][2], 0, 0, 0);
    acc[1][3] = __builtin_amdgcn_mfma_f32_16x16x32_bf16(a1, b3, acc[1][3], 0, 0, 0);
  }

  // epilogue: C/D map col = lane&15, row = khalf*4 + r  [verified m89/m91]
  int rbase = khalf * 4;
#pragma unroll
  for (int j = 0; j < 4; ++j) {
    int colL = nbase + j * 16 + l16;
    float bias = biasv[b * L + colL];
#pragma unroll
    for (int i = 0; i < 2; ++i) {
#pragma unroll
      for (int r = 0; r < 4; ++r) {
        int t = mbase + i * 16 + rbase + r;
        logpT[((size_t)b * tc + (t - t_begin)) * L + colL] = f2bf(acc[i][j][r] + bias);
      }
    }
  }
}

// ---------------- scan: 4 waves, 4 cols/lane, wide reads, pipelined lgkm --------
// Wave w spans cols [128w-128, 128w+128) (4 contiguous cols/lane -> one
// ds_read_b64 per step), OWNS the top 128 (lanes 32-63). 128-col left halo =
// 128-step staleness budget; we sync every 32 rows (4x margin). Wave0's lanes
// 0-31 cover negative cols: reads clamped, carries pinned ~-1e30 (max-plus
// monotone => harmless). Staging: each wave DMAs its own 8 rows/phase into a
// 2-slot LDS ring (raw s_barrier + vmcnt(8), pipeline survives barriers - R14).
// Compute: 4-row blocks, 2-block read-ahead, counted lgkmcnt(4) (max 8
// outstanding <= 15) - ds latency paid once per phase, not per block.
#define SROWS 32

#define VMW(n)                                             \
  do {                                                     \
    asm volatile("s_waitcnt vmcnt(" #n ")" ::: "memory");  \
    __builtin_amdgcn_sched_barrier(0);                     \
  } while (0)
#define LGKMC(n)                                           \
  do {                                                     \
    asm volatile("s_waitcnt lgkmcnt(" #n ")" ::: "memory");\
    __builtin_amdgcn_sched_barrier(0);                     \
  } while (0)
#define BAR()                                              \
  do {                                                     \
    asm volatile("" ::: "memory");                         \
    __builtin_amdgcn_s_barrier();                          \
    asm volatile("" ::: "memory");                         \
  } while (0)
#define RD64(dst, addr, imm) \
  asm volatile("ds_read_b64 %0, %1 offset:%c2" : "=v"(dst) : "v"(addr), "i"(imm))
#define RD4(P, base_)                 \
  do {                                \
    RD64(P##0, ringA, (base_));       \
    RD64(P##1, ringA, (base_) + 1024);\
    RD64(P##2, ringA, (base_) + 2048);\
    RD64(P##3, ringA, (base_) + 3072);\
  } while (0)
#define S4(P)                                     \
  do { stepv(P##0); stepv(P##1); stepv(P##2); stepv(P##3); } while (0)

__device__ __forceinline__ float dpp_shr1_neginf(float x) {
  int r = __builtin_amdgcn_update_dpp(__float_as_int(NEG_INF), __float_as_int(x),
                                      0x138, 0xf, 0xf, false);  // wave_shr:1
  return __int_as_float(r);
}

__global__ __launch_bounds__(256, 1) void scan_kernel(const u16* __restrict__ logpT,
                                                      const int* __restrict__ mel_len,
                                                      const int* __restrict__ text_len,
                                                      float* __restrict__ carry_ws,
                                                      float* __restrict__ la_ws,
                                                      int t_begin, int tc) {
  __shared__ u16 ring[2][SROWS][L];   // 64 KB
  __shared__ float smem[2][L];        // 4 KB halo exchange
  int tid = threadIdx.x;
  int wave = tid >> 6;
  int lane = tid & 63;
  int b = blockIdx.x;
  int ml = get_len(mel_len, b);
  int tl = get_len(text_len, b);
  const u16* base0 = logpT + (size_t)b * tc * L;
  float* cws = carry_ws + b * L;
  int col_lane = 128 * wave - 128 + 4 * lane;   // first of 4 cols (may be <0)
  int cl = (col_lane < 0) ? 0 : col_lane;       // clamped for loads
  bool owner = (lane >= 32);                    // owns cols 128w..128w+127

  float c0 = NEG_INF, c1 = NEG_INF, c2 = NEG_INF, c3 = NEG_INF;
  int tstart;
  if (t_begin == 0) {
    if (wave == 0 && lane == 32) c0 = __uint_as_float((u32)base0[0] << 16);
    tstart = 1;
  } else {
    float4 v = *(const float4*)(cws + cl);
    c0 = v.x; c1 = v.y; c2 = v.z; c3 = v.w;
    if (col_lane < 0) { c0 = NEG_INF; c1 = NEG_INF; c2 = NEG_INF; c3 = NEG_INF; }
    tstart = t_begin;
  }

  int tstop = min(t_begin + tc, ml);
  int nrows = tstop - tstart;

  auto stepv = [&](u32x2 v) {
    float p = dpp_shr1_neginf(c3);  // lane-1's old c3; lane0 <- NEG_INF
    float f0 = __uint_as_float(v.x << 16);
    float f1 = __uint_as_float(v.x & 0xFFFF0000u);
    float f2 = __uint_as_float(v.y << 16);
    float f3 = __uint_as_float(v.y & 0xFFFF0000u);
    c3 = fmaxf(c3, c2) + f3;
    c2 = fmaxf(c2, c1) + f2;
    c1 = fmaxf(c1, c0) + f1;
    c0 = fmaxf(c0, p) + f0;
  };

  if (nrows > 0) {
    int np = (nrows + SROWS - 1) / SROWS;
    int tlast = tstop - 1;

    auto stage = [&](int ph) -> bool {  // each wave DMAs its own 8 rows
      if (ph >= np) return false;
      int pr = tstart + ph * SROWS + 8 * wave;
      u16* d0 = &ring[ph & 1][8 * wave][0];
#pragma unroll
      for (int j = 0; j < 8; ++j) {
        int t = pr + j;
        t = (t > tlast) ? tlast : t;  // clamp; dup rows unread
        const u16* s = base0 + (size_t)(t - t_begin) * L + lane * 8;
        __builtin_amdgcn_global_load_lds(
            (const __attribute__((address_space(1))) void*)s,
            (__attribute__((address_space(3))) void*)(d0 + (size_t)j * L + lane * 8),
            16, 0, 0);
      }
      return true;
    };

    stage(0);
    for (int k = 0; k < np; ++k) {
      BAR();  // slot (k+1)&1 free (phase k-1 consumed)
      bool nx = stage(k + 1);
      if (nx) VMW(8); else VMW(0);  // own phase-k loads landed
      BAR();  // all waves' phase-k rows in LDS; smem[(k-1)&1] visible
      if (k > 0 && wave > 0 && lane < 32) {  // exact halo refresh
        float4 h = *(const float4*)&smem[(k - 1) & 1][col_lane];
        c0 = h.x; c1 = h.y; c2 = h.z; c3 = h.w;
      }
      int pstart = tstart + k * SROWS;
      int rem = tstop - pstart;
      if (rem > SROWS) rem = SROWS;
      u32 ringA = (u32)(uintptr_t)(__attribute__((address_space(3)))
                                   u16*)(&ring[k & 1][0][0]) +
                  2u * (u32)cl;
      if (rem == SROWS) {
        u32x2 qA0, qA1, qA2, qA3, qB0, qB1, qB2, qB3;
        RD4(qA, 0);     RD4(qB, 4096);
        LGKMC(4); S4(qA); RD4(qA, 8192);
        LGKMC(4); S4(qB); RD4(qB, 12288);
        LGKMC(4); S4(qA); RD4(qA, 16384);
        LGKMC(4); S4(qB); RD4(qB, 20480);
        LGKMC(4); S4(qA); RD4(qA, 24576);
        LGKMC(4); S4(qB); RD4(qB, 28672);
        LGKMC(4); S4(qA);
        LGKMC(0); S4(qB);
      } else {
        const char* rp = (const char*)(&ring[k & 1][0][0]) + 2 * cl;
        for (int r = 0; r < rem; ++r) {
          u32x2 v = *(const u32x2*)(rp + (size_t)r * (L * 2));
          stepv(v);
        }
      }
      if (owner) {  // publish owned cols for next phase's halo refresh
        *(float4*)&smem[k & 1][col_lane] = make_float4(c0, c1, c2, c3);
      }
      LGKMC(0);  // ds_write visible before next barrier
    }
  }

  // persist carry (owned cols only)
  if (owner) *(float4*)(cws + col_lane) = make_float4(c0, c1, c2, c3);

  if (t_begin + tc >= T) {  // last chunk: la[b] = alpha[ml-1][tl-1]
    int li = tl - 1;
    int w_own = li >> 7;
    if (wave == w_own) {
      int sub = li & 3;
      float v = (sub == 0) ? c0 : (sub == 1) ? c1 : (sub == 2) ? c2 : c3;
      float lav = __shfl(v, 32 + ((li & 127) >> 2));
      if (lane == 0) la_ws[b] = lav;
    }
  }
}

__global__ __launch_bounds__(64) void reduce_kernel(const float* __restrict__ la_ws,
                                                    float* __restrict__ out) {
  int lane = threadIdx.x;
  float v = (lane < B) ? la_ws[lane] : 0.f;
#pragma unroll
  for (int s = 32; s > 0; s >>= 1) v += __shfl_down(v, s);
  if (lane == 0) out[0] = -v * (1.0f / (float)B);
}

extern "C" void kernel_launch(void* const* d_in, const int* in_sizes, int n_in,
                              void* d_out, int out_size, void* d_ws, size_t ws_size,
                              hipStream_t stream) {
  const float* mu_sigma = (const float*)d_in[0];
  const float* melspec  = (const float*)d_in[1];
  const int*   text_len = (const int*)d_in[2];
  const int*   mel_len  = (const int*)d_in[3];
  float* out = (float*)d_out;

  char* ws = (char*)d_ws;
  size_t off = 0;
  u16* Wfrag = (u16*)(ws + off);         off += (size_t)B * KDIM * L * 2;      // 5.2 MB
  float* biasv = (float*)(ws + off);     off += (size_t)B * L * 4;
  float* carry_ws = (float*)(ws + off);  off += (size_t)B * L * 4;
  float* la_ws = (float*)(ws + off);     off += 256;
  u16* Xfrag = (u16*)(ws + off);         off += (size_t)B * KDIM * T * 2;      // 21 MB
  u16* logpT = (u16*)(ws + off);
  size_t avail = (ws_size > off) ? (ws_size - off) : 0;
  size_t per_t = (size_t)B * L * 2;  // bytes per t-slice across all b (bf16)
  long long tcl = (long long)(avail / per_t);
  int Tc = (tcl > T) ? T : (int)tcl;
  Tc &= ~63;
  if (Tc < 64) return;  // insufficient workspace (not expected)

  prep_kernel<<<dim3((B * L + 255) / 256), 256, 0, stream>>>(mu_sigma, Wfrag, biasv);
  xprep_kernel<<<dim3((B * 10 * T) / 256), 256, 0, stream>>>(melspec, Xfrag);

  for (int t_begin = 0; t_begin < T; t_begin += Tc) {
    int tc = (T - t_begin < Tc) ? (T - t_begin) : Tc;
    dim3 grid(tc / 64, L / 128, B);
    gemm_logp<<<grid, 256, 0, stream>>>(Xfrag, Wfrag, biasv, mel_len, text_len,
                                        logpT, t_begin, tc);
    scan_kernel<<<dim3(B), 256, 0, stream>>>(logpT, mel_len, text_len, carry_ws,
                                             la_ws, t_begin, tc);
  }
  reduce_kernel<<<1, 64, 0, stream>>>(la_ws, out);
}